// Round 1
// baseline (1803.473 us; speedup 1.0000x reference)
//
#include <hip/hip_runtime.h>

#define D 32

// K0: P_src = W_aggr @ W_eu @ W_src, similarly edge, rx. One block (32,32).
__global__ void combine_weights(const float* __restrict__ W_src,
                                const float* __restrict__ W_edge,
                                const float* __restrict__ W_rx,
                                const float* __restrict__ W_eu,
                                const float* __restrict__ W_aggr,
                                float* __restrict__ P_out /* 3*D*D: src, edge, rx */) {
    __shared__ float sWa[D][D], sWe[D][D], sP2[D][D + 1];
    __shared__ float sW1[D][D], sW2[D][D], sW3[D][D];
    const int j = threadIdx.x, i = threadIdx.y;
    sWa[i][j] = W_aggr[i * D + j];
    sWe[i][j] = W_eu[i * D + j];
    sW1[i][j] = W_src[i * D + j];
    sW2[i][j] = W_edge[i * D + j];
    sW3[i][j] = W_rx[i * D + j];
    __syncthreads();
    float s = 0.f;
    #pragma unroll
    for (int k = 0; k < D; ++k) s += sWa[i][k] * sWe[k][j];
    sP2[i][j] = s;
    __syncthreads();
    float a = 0.f, b = 0.f, c = 0.f;
    #pragma unroll
    for (int k = 0; k < D; ++k) {
        const float p = sP2[i][k];
        a += p * sW1[k][j];
        b += p * sW2[k][j];
        c += p * sW3[k][j];
    }
    P_out[0 * D * D + i * D + j] = a;
    P_out[1 * D * D + i * D + j] = b;
    P_out[2 * D * D + i * D + j] = c;
}

// K1: per-edge scatter. 8 threads per edge, each owns a float4 slice.
// A[v] += x[u]; B[v] += edge_attr[e]; deg[v] += 1.
__global__ void __launch_bounds__(256) edge_scatter(
    const float* __restrict__ x,
    const int* __restrict__ ei,      // [2, E] int32
    const float* __restrict__ ea,    // [E, D]
    float* __restrict__ A,
    float* __restrict__ B,
    float* __restrict__ deg,
    int E_) {
    const int t = blockIdx.x * 256 + threadIdx.x;
    const int e = t >> 3;
    const int q = t & 7;
    if (e >= E_) return;
    const int u = ei[e];
    const int v = ei[E_ + e];
    const float4 ev = *(const float4*)(ea + (size_t)e * D + q * 4);
    const float4 xv = *(const float4*)(x + (size_t)u * D + q * 4);
    float* Ar = A + (size_t)v * D + q * 4;
    float* Br = B + (size_t)v * D + q * 4;
    atomicAdd(Ar + 0, xv.x);
    atomicAdd(Ar + 1, xv.y);
    atomicAdd(Ar + 2, xv.z);
    atomicAdd(Ar + 3, xv.w);
    atomicAdd(Br + 0, ev.x);
    atomicAdd(Br + 1, ev.y);
    atomicAdd(Br + 2, ev.z);
    atomicAdd(Br + 3, ev.w);
    if (q == 0) atomicAdd(deg + v, 1.0f);
}

// K2: per-node epilogue. Thread = node. Weights are wave-uniform loads
// (compiler emits s_load) -> v_fmac with SGPR operand; x/A/B rows via float4.
__global__ void __launch_bounds__(256) node_kernel(
    const float* __restrict__ x,
    const float* __restrict__ A,
    const float* __restrict__ B,
    const float* __restrict__ deg,
    const float* __restrict__ W_rxnode,  // [D,D] row-major, use W[j*D+k]
    const float* __restrict__ P,         // P_src, P_edge, P_rx each [D,D]
    float* __restrict__ out0,
    float* __restrict__ out1,
    int N_) {
    const int n = blockIdx.x * 256 + threadIdx.x;
    if (n >= N_) return;

    float xr[D];
    #pragma unroll
    for (int kq = 0; kq < D / 4; ++kq)
        *(float4*)(xr + kq * 4) = *(const float4*)(x + (size_t)n * D + kq * 4);

    // ---- out0 = x @ W_rxnode.T ----
    {
        float o[D];
        #pragma unroll
        for (int j = 0; j < D; ++j) {
            float s = 0.f;
            #pragma unroll
            for (int k = 0; k < D; ++k) s += xr[k] * W_rxnode[j * D + k];
            o[j] = s;
        }
        #pragma unroll
        for (int kq = 0; kq < D / 4; ++kq)
            *(float4*)(out0 + (size_t)n * D + kq * 4) = *(const float4*)(o + kq * 4);
    }

    // ---- out1 = A@P_src.T + B@P_edge.T + deg*(x@P_rx.T) ----
    float Ar[D], Br[D];
    #pragma unroll
    for (int kq = 0; kq < D / 4; ++kq) {
        *(float4*)(Ar + kq * 4) = *(const float4*)(A + (size_t)n * D + kq * 4);
        *(float4*)(Br + kq * 4) = *(const float4*)(B + (size_t)n * D + kq * 4);
    }
    const float dg = deg[n];
    #pragma unroll
    for (int k = 0; k < D; ++k) xr[k] *= dg;  // fold deg into x row

    const float* __restrict__ Ps = P;
    const float* __restrict__ Pe = P + D * D;
    const float* __restrict__ Pr = P + 2 * D * D;
    {
        float o[D];
        #pragma unroll
        for (int j = 0; j < D; ++j) {
            float s = 0.f;
            #pragma unroll
            for (int k = 0; k < D; ++k) {
                s += Ar[k] * Ps[j * D + k];
                s += Br[k] * Pe[j * D + k];
                s += xr[k] * Pr[j * D + k];
            }
            o[j] = s;
        }
        #pragma unroll
        for (int kq = 0; kq < D / 4; ++kq)
            *(float4*)(out1 + (size_t)n * D + kq * 4) = *(const float4*)(o + kq * 4);
    }
}

extern "C" void kernel_launch(void* const* d_in, const int* in_sizes, int n_in,
                              void* d_out, int out_size, void* d_ws, size_t ws_size,
                              hipStream_t stream) {
    const float* x        = (const float*)d_in[0];
    const int*   ei       = (const int*)d_in[1];    // [2, E]
    const float* ea       = (const float*)d_in[2];  // [E, D]
    const float* W_src    = (const float*)d_in[3];
    const float* W_edge   = (const float*)d_in[4];
    const float* W_rx     = (const float*)d_in[5];
    const float* W_eu     = (const float*)d_in[6];
    const float* W_rxnode = (const float*)d_in[7];
    const float* W_aggr   = (const float*)d_in[8];

    const int N_ = in_sizes[0] / D;  // 100000
    const int E_ = in_sizes[2] / D;  // 2000000

    float* A   = (float*)d_ws;               // [N, D]
    float* B   = A + (size_t)N_ * D;         // [N, D]
    float* deg = B + (size_t)N_ * D;         // [N]
    float* P   = deg + N_;                   // [3, D, D]

    float* out0 = (float*)d_out;             // rx_node_embed
    float* out1 = out0 + (size_t)N_ * D;     // rx_aggregated_edges

    // zero accumulators every call (graph replays re-run this node)
    hipMemsetAsync(d_ws, 0, ((size_t)2 * N_ * D + N_) * sizeof(float), stream);

    combine_weights<<<1, dim3(32, 32), 0, stream>>>(W_src, W_edge, W_rx, W_eu, W_aggr, P);

    const int edge_threads = E_ * 8;
    edge_scatter<<<(edge_threads + 255) / 256, 256, 0, stream>>>(x, ei, ea, A, B, deg, E_);

    node_kernel<<<(N_ + 255) / 256, 256, 0, stream>>>(x, A, B, deg, W_rxnode, P, out0, out1, N_);
}

// Round 2
// 386.114 us; speedup vs baseline: 4.6708x; 4.6708x over previous
//
#include <hip/hip_runtime.h>

#define D 32
#define CAPMAX 96

__global__ void combine_weights(const float* __restrict__ W_src,
                                const float* __restrict__ W_edge,
                                const float* __restrict__ W_rx,
                                const float* __restrict__ W_eu,
                                const float* __restrict__ W_aggr,
                                float* __restrict__ P_out) {
    __shared__ float sWa[D][D], sWe[D][D], sP2[D][D + 1];
    __shared__ float sW1[D][D], sW2[D][D], sW3[D][D];
    const int j = threadIdx.x, i = threadIdx.y;
    sWa[i][j] = W_aggr[i * D + j];
    sWe[i][j] = W_eu[i * D + j];
    sW1[i][j] = W_src[i * D + j];
    sW2[i][j] = W_edge[i * D + j];
    sW3[i][j] = W_rx[i * D + j];
    __syncthreads();
    float s = 0.f;
    #pragma unroll
    for (int k = 0; k < D; ++k) s += sWa[i][k] * sWe[k][j];
    sP2[i][j] = s;
    __syncthreads();
    float a = 0.f, b = 0.f, c = 0.f;
    #pragma unroll
    for (int k = 0; k < D; ++k) {
        const float p = sP2[i][k];
        a += p * sW1[k][j];
        b += p * sW2[k][j];
        c += p * sW3[k][j];
    }
    P_out[0 * D * D + i * D + j] = a;
    P_out[1 * D * D + i * D + j] = b;
    P_out[2 * D * D + i * D + j] = c;
}

__global__ void __launch_bounds__(256) scatter_edges(
    const float* __restrict__ x,
    const int* __restrict__ ei,
    const float* __restrict__ ea,
    int* __restrict__ cnt,
    int* __restrict__ bucket,
    int CAP,
    float* __restrict__ A,
    float* __restrict__ B,
    int E_) {
    const int e = blockIdx.x * 256 + threadIdx.x;
    if (e >= E_) return;
    const int v = ei[E_ + e];
    const int pos = atomicAdd(&cnt[v], 1);
    if (pos < CAP) {
        bucket[(size_t)v * CAP + pos] = e;
    } else {
        const int u = ei[e];
        const float* xr = x + (size_t)u * D;
        const float* er = ea + (size_t)e * D;
        float* Ar = A + (size_t)v * D;
        float* Br = B + (size_t)v * D;
        for (int k = 0; k < D; ++k) {
            atomicAdd(Ar + k, xr[k]);
            atomicAdd(Br + k, er[k]);
        }
    }
}

__global__ void __launch_bounds__(256) gather_nodes(
    const float* __restrict__ x,
    const int* __restrict__ ei,
    const float* __restrict__ ea,
    const int* __restrict__ cnt,
    const int* __restrict__ bucket,
    int CAP,
    float* __restrict__ A,
    float* __restrict__ B,
    int N_) {
    const int t = blockIdx.x * 256 + threadIdx.x;
    const int n = t >> 3;
    const int q = t & 7;
    if (n >= N_) return;
    int c = cnt[n];
    if (c > CAP) c = CAP;
    const int* bk = bucket + (size_t)n * CAP;
    float ax = 0.f, ay = 0.f, az = 0.f, aw = 0.f;
    float bx = 0.f, by = 0.f, bz = 0.f, bw = 0.f;
    int e0 = 0, u0 = 0;
    if (c > 0) { e0 = bk[0]; u0 = ei[e0]; }
    for (int i = 0; i < c; ++i) {
        int e1 = e0, u1 = u0;
        if (i + 1 < c) { e1 = bk[i + 1]; u1 = ei[e1]; }
        const float4 xv = *(const float4*)(x + (size_t)u0 * D + q * 4);
        const float4 ev = *(const float4*)(ea + (size_t)e0 * D + q * 4);
        ax += xv.x; ay += xv.y; az += xv.z; aw += xv.w;
        bx += ev.x; by += ev.y; bz += ev.z; bw += ev.w;
        e0 = e1; u0 = u1;
    }
    float* Ar = A + (size_t)n * D + q * 4;
    float* Br = B + (size_t)n * D + q * 4;
    const float4 Ao = *(const float4*)Ar;
    const float4 Bo = *(const float4*)Br;
    float4 An = { Ao.x + ax, Ao.y + ay, Ao.z + az, Ao.w + aw };
    float4 Bn = { Bo.x + bx, Bo.y + by, Bo.z + bz, Bo.w + bw };
    *(float4*)Ar = An;
    *(float4*)Br = Bn;
}

__global__ void __launch_bounds__(256) node_kernel(
    const float* __restrict__ x,
    const float* __restrict__ A,
    const float* __restrict__ B,
    const int* __restrict__ cnt,
    const float* __restrict__ W_rxnode,
    const float* __restrict__ P,
    float* __restrict__ out0,
    float* __restrict__ out1,
    int N_) {
    const int n = blockIdx.x * 256 + threadIdx.x;
    if (n >= N_) return;

    float xr[D];
    #pragma unroll
    for (int kq = 0; kq < D / 4; ++kq)
        *(float4*)(xr + kq * 4) = *(const float4*)(x + (size_t)n * D + kq * 4);

    {
        float o[D];
        #pragma unroll
        for (int j = 0; j < D; ++j) {
            float s = 0.f;
            #pragma unroll
            for (int k = 0; k < D; ++k) s += xr[k] * W_rxnode[j * D + k];
            o[j] = s;
        }
        #pragma unroll
        for (int kq = 0; kq < D / 4; ++kq)
            *(float4*)(out0 + (size_t)n * D + kq * 4) = *(const float4*)(o + kq * 4);
    }

    float Ar[D], Br[D];
    #pragma unroll
    for (int kq = 0; kq < D / 4; ++kq) {
        *(float4*)(Ar + kq * 4) = *(const float4*)(A + (size_t)n * D + kq * 4);
        *(float4*)(Br + kq * 4) = *(const float4*)(B + (size_t)n * D + kq * 4);
    }
    const float dg = (float)cnt[n];
    #pragma unroll
    for (int k = 0; k < D; ++k) xr[k] *= dg;

    const float* __restrict__ Ps = P;
    const float* __restrict__ Pe = P + D * D;
    const float* __restrict__ Pr = P + 2 * D * D;
    {
        float o[D];
        #pragma unroll
        for (int j = 0; j < D; ++j) {
            float s = 0.f;
            #pragma unroll
            for (int k = 0; k < D; ++k) {
                s += Ar[k] * Ps[j * D + k];
                s += Br[k] * Pe[j * D + k];
                s += xr[k] * Pr[j * D + k];
            }
            o[j] = s;
        }
        #pragma unroll
        for (int kq = 0; kq < D / 4; ++kq)
            *(float4*)(out1 + (size_t)n * D + kq * 4) = *(const float4*)(o + kq * 4);
    }
}

extern "C" void kernel_launch(void* const* d_in, const int* in_sizes, int n_in,
                              void* d_out, int out_size, void* d_ws, size_t ws_size,
                              hipStream_t stream) {
    const float* x        = (const float*)d_in[0];
    const int*   ei       = (const int*)d_in[1];
    const float* ea       = (const float*)d_in[2];
    const float* W_src    = (const float*)d_in[3];
    const float* W_edge   = (const float*)d_in[4];
    const float* W_rx     = (const float*)d_in[5];
    const float* W_eu     = (const float*)d_in[6];
    const float* W_rxnode = (const float*)d_in[7];
    const float* W_aggr   = (const float*)d_in[8];

    const int N_ = in_sizes[0] / D;
    const int E_ = in_sizes[2] / D;

    float* A      = (float*)d_ws;
    float* B      = A + (size_t)N_ * D;
    int*   cnt    = (int*)(B + (size_t)N_ * D);
    float* P      = (float*)(cnt + N_);
    int*   bucket = (int*)(P + 3 * D * D);

    const size_t fixed_bytes = ((size_t)2 * N_ * D + N_ + 3 * D * D) * 4;
    int CAP = 0;
    if (ws_size > fixed_bytes) {
        size_t c = (ws_size - fixed_bytes) / ((size_t)N_ * 4);
        CAP = (c > CAPMAX) ? CAPMAX : (int)c;
    }

    float* out0 = (float*)d_out;
    float* out1 = out0 + (size_t)N_ * D;

    hipMemsetAsync(d_ws, 0, ((size_t)2 * N_ * D + N_) * sizeof(float), stream);

    combine_weights<<<1, dim3(32, 32), 0, stream>>>(W_src, W_edge, W_rx, W_eu, W_aggr, P);

    scatter_edges<<<(E_ + 255) / 256, 256, 0, stream>>>(x, ei, ea, cnt, bucket, CAP, A, B, E_);

    gather_nodes<<<((N_ * 8) + 255) / 256, 256, 0, stream>>>(x, ei, ea, cnt, bucket, CAP, A, B, N_);

    node_kernel<<<(N_ + 255) / 256, 256, 0, stream>>>(x, A, B, cnt, W_rxnode, P, out0, out1, N_);
}